// Round 3
// baseline (451.828 us; speedup 1.0000x reference)
//
#include <hip/hip_runtime.h>
#include <math.h>

#define NN 2048
#define DD 128
#define HH 8
#define DHH 16
#define EDIM 8
#define EHID 32

// ---------------- Kernel 1: Q,K,V projections + folded edge projection QW ----
// grid 256 x 384 threads, 8 rows per block.
__global__ __launch_bounds__(384) void proj_kernel(
    const float* __restrict__ X,
    const float* __restrict__ Wq, const float* __restrict__ Wk,
    const float* __restrict__ Wv, const float* __restrict__ We,
    const float* __restrict__ Wr,
    float* __restrict__ Qo, float* __restrict__ Ko,
    float* __restrict__ Vo, float* __restrict__ QWo) {
  __shared__ float x_lds[8][128];
  __shared__ float wer_lds[8][128];   // (We@Wr)[e][c]
  __shared__ float q_lds[8][128];
  const int t = threadIdx.x;
  const int i0 = blockIdx.x * 8;

  for (int idx = t; idx < 8 * 128; idx += 384)
    x_lds[idx >> 7][idx & 127] = X[(size_t)i0 * 128 + idx];

  if (t < 128) {
    float acc[EDIM];
#pragma unroll
    for (int e = 0; e < EDIM; ++e) acc[e] = 0.f;
    for (int k = 0; k < EHID; ++k) {
      const float wr = Wr[k * 128 + t];
#pragma unroll
      for (int e = 0; e < EDIM; ++e) acc[e] = fmaf(We[e * EHID + k], wr, acc[e]);
    }
#pragma unroll
    for (int e = 0; e < EDIM; ++e) wer_lds[e][t] = acc[e];
  }
  __syncthreads();

  const int mat = t >> 7;       // 0=Q 1=K 2=V
  const int c = t & 127;
  const float* __restrict__ W = (mat == 0) ? Wq : ((mat == 1) ? Wk : Wv);
  float acc[8];
#pragma unroll
  for (int r = 0; r < 8; ++r) acc[r] = 0.f;
  for (int d = 0; d < 128; ++d) {
    const float w = W[d * 128 + c];
#pragma unroll
    for (int r = 0; r < 8; ++r) acc[r] = fmaf(x_lds[r][d], w, acc[r]);
  }
  float* __restrict__ Out = (mat == 0) ? Qo : ((mat == 1) ? Ko : Vo);
#pragma unroll
  for (int r = 0; r < 8; ++r) Out[(size_t)(i0 + r) * 128 + c] = acc[r];
  if (mat == 0) {
#pragma unroll
    for (int r = 0; r < 8; ++r) q_lds[r][c] = acc[r];
  }
  __syncthreads();

  // QW[i][h*8+e] = sum_d Q[i][h*16+d] * Wer[e][h*16+d]
  if (t < 64) {
    const int h = t >> 3, e = t & 7;
    for (int r = 0; r < 8; ++r) {
      float s = 0.f;
#pragma unroll
      for (int d = 0; d < DHH; ++d)
        s = fmaf(q_lds[r][h * DHH + d], wer_lds[e][h * DHH + d], s);
      QWo[(size_t)(i0 + r) * 64 + h * 8 + e] = s;
    }
  }
}

// ---------------- Kernel 2: fused masked edge-biased attention + O@Wo -------
// grid 256 blocks (8 rows each), 1024 threads.
// thread = (il 0..7, h 0..7, jo 0..15); each owns (i,h) over j in [jo*128, ...)
// Scores kept in the log2 domain: s2 = log2(e)*leaky(raw/4) so p = exp2(s2-m)
// is a bare v_exp_f32. leaky(c*s)=c*leaky(s) for c>0 makes the fold exact:
//   0.25*log2e*(0.6*s + 0.4*|s|) = 0.21640425*s + 0.14426950*|s|.
__global__ __launch_bounds__(1024) void attn_kernel(
    const float* __restrict__ Qg, const float* __restrict__ Kg,
    const float* __restrict__ Vg, const float* __restrict__ QWg,
    const int* __restrict__ adj, const float* __restrict__ Eg,
    const float* __restrict__ Wo, float* __restrict__ out) {
  const int t = threadIdx.x;
  const int il = t & 7;
  const int h = (t >> 3) & 7;
  const int jo = t >> 6;              // == wave id, 0..15
  const int i0 = blockIdx.x * 8;
  const int i = i0 + il;

  float q[16], qw[8];
  {
    const float4* qp = (const float4*)(Qg + (size_t)i * 128 + h * 16);
#pragma unroll
    for (int d4 = 0; d4 < 4; ++d4) {
      const float4 v = qp[d4];
      q[4 * d4 + 0] = v.x; q[4 * d4 + 1] = v.y;
      q[4 * d4 + 2] = v.z; q[4 * d4 + 3] = v.w;
    }
    const float4* wp = (const float4*)(QWg + (size_t)i * 64 + h * 8);
    const float4 w0 = wp[0], w1 = wp[1];
    qw[0] = w0.x; qw[1] = w0.y; qw[2] = w0.z; qw[3] = w0.w;
    qw[4] = w1.x; qw[5] = w1.y; qw[6] = w1.z; qw[7] = w1.w;
  }

  float acc[16];
#pragma unroll
  for (int d = 0; d < 16; ++d) acc[d] = 0.f;
  float m = -INFINITY, mt = -INFINITY, l = 0.f;

  const int jbase = jo * 128;
  const int4* __restrict__ ap4 = (const int4*)(adj + (size_t)i * NN + jbase);
  const float4* __restrict__ ep = (const float4*)Eg + ((size_t)i * NN + jbase) * 2;
  const float4* __restrict__ kp = (const float4*)Kg + (size_t)jbase * 32 + h * 4;
  const float4* __restrict__ vp = (const float4*)Vg + (size_t)jbase * 32 + h * 4;

  for (int j4 = 0; j4 < 32; ++j4) {
    const int4 a4 = ap4[j4];
#pragma unroll
    for (int u4 = 0; u4 < 4; ++u4) {
      const int jj = j4 * 4 + u4;
      const int a = (u4 == 0) ? a4.x : (u4 == 1) ? a4.y : (u4 == 2) ? a4.z : a4.w;
      const float4 e0 = ep[2 * jj], e1 = ep[2 * jj + 1];
      const float4 k0 = kp[jj * 32 + 0];
      const float4 k1 = kp[jj * 32 + 1];
      const float4 k2 = kp[jj * 32 + 2];
      const float4 k3 = kp[jj * 32 + 3];
      float s0 = q[0] * k0.x;   s0 = fmaf(q[1], k0.y, s0);
      s0 = fmaf(q[2], k0.z, s0);  s0 = fmaf(q[3], k0.w, s0);
      s0 = fmaf(q[4], k1.x, s0);  s0 = fmaf(q[5], k1.y, s0);
      s0 = fmaf(q[6], k1.z, s0);  s0 = fmaf(q[7], k1.w, s0);
      float s1 = q[8] * k2.x;   s1 = fmaf(q[9], k2.y, s1);
      s1 = fmaf(q[10], k2.z, s1); s1 = fmaf(q[11], k2.w, s1);
      s1 = fmaf(q[12], k3.x, s1); s1 = fmaf(q[13], k3.y, s1);
      s1 = fmaf(q[14], k3.z, s1); s1 = fmaf(q[15], k3.w, s1);
      float b0 = qw[0] * e0.x;  b0 = fmaf(qw[1], e0.y, b0);
      b0 = fmaf(qw[2], e0.z, b0); b0 = fmaf(qw[3], e0.w, b0);
      b0 = fmaf(qw[4], e1.x, b0); b0 = fmaf(qw[5], e1.y, b0);
      b0 = fmaf(qw[6], e1.z, b0); b0 = fmaf(qw[7], e1.w, b0);
      const float raw = (s0 + s1) + b0;
      // scale + leaky-relu + log2e, folded
      float s2 = fmaf(0.14426950f, fabsf(raw), 0.21640425f * raw);
      s2 = (a > 0) ? s2 : -1e9f;      // adjacency mask (after leaky, like ref)
      if (s2 > mt) {                  // deferred-rescale online softmax (T13)
        const float sc = exp2f(m - s2);
        l *= sc;
#pragma unroll
        for (int d = 0; d < 16; ++d) acc[d] *= sc;
        m = s2;
        mt = s2 + 12.f;
      }
      const float p = exp2f(s2 - m);
      l += p;
      const float4 v0 = vp[jj * 32 + 0];
      const float4 v1 = vp[jj * 32 + 1];
      const float4 v2 = vp[jj * 32 + 2];
      const float4 v3 = vp[jj * 32 + 3];
      acc[0]  = fmaf(p, v0.x, acc[0]);  acc[1]  = fmaf(p, v0.y, acc[1]);
      acc[2]  = fmaf(p, v0.z, acc[2]);  acc[3]  = fmaf(p, v0.w, acc[3]);
      acc[4]  = fmaf(p, v1.x, acc[4]);  acc[5]  = fmaf(p, v1.y, acc[5]);
      acc[6]  = fmaf(p, v1.z, acc[6]);  acc[7]  = fmaf(p, v1.w, acc[7]);
      acc[8]  = fmaf(p, v2.x, acc[8]);  acc[9]  = fmaf(p, v2.y, acc[9]);
      acc[10] = fmaf(p, v2.z, acc[10]); acc[11] = fmaf(p, v2.w, acc[11]);
      acc[12] = fmaf(p, v3.x, acc[12]); acc[13] = fmaf(p, v3.y, acc[13]);
      acc[14] = fmaf(p, v3.z, acc[14]); acc[15] = fmaf(p, v3.w, acc[15]);
    }
  }

  // ---- merge the 16 jo-partials per (il,h): LDS log-tree, 4 rounds ----
  // stride 18 floats -> consecutive u differ by 18 banks: 2-way alias, free.
  __shared__ float mbuf[512 * 18];    // 36 KB
  __shared__ float o_lds[8][128];     // 4 KB
  const int u = t & 63;               // (il,h) id
  for (int k = 8; k >= 1; k >>= 1) {
    if (jo >= k && jo < 2 * k) {
      float* b = mbuf + ((size_t)((jo - k) * 64 + u)) * 18;
      b[0] = m; b[1] = l;
#pragma unroll
      for (int d = 0; d < 16; ++d) b[2 + d] = acc[d];
    }
    __syncthreads();
    if (jo < k) {
      const float* b = mbuf + ((size_t)(jo * 64 + u)) * 18;
      const float m2 = b[0], l2 = b[1];
      const float M = fmaxf(m, m2);
      const float sa = exp2f(m - M), sb = exp2f(m2 - M);
      l = l * sa + l2 * sb;
#pragma unroll
      for (int d = 0; d < 16; ++d) acc[d] = acc[d] * sa + b[2 + d] * sb;
      m = M;
    }
    __syncthreads();
  }

  if (jo == 0) {
    const float inv = 1.f / l;
#pragma unroll
    for (int d = 0; d < 16; ++d) o_lds[il][h * 16 + d] = acc[d] * inv;
  }
  __syncthreads();

  // ---- epilogue: out = O @ Wo ----
  const int r = t >> 7;               // 0..7
  const int c = t & 127;
  float s = 0.f;
  for (int d = 0; d < 128; ++d)
    s = fmaf(o_lds[r][d], Wo[d * 128 + c], s);
  out[(size_t)(i0 + r) * 128 + c] = s;
}

extern "C" void kernel_launch(void* const* d_in, const int* in_sizes, int n_in,
                              void* d_out, int out_size, void* d_ws, size_t ws_size,
                              hipStream_t stream) {
  const float* X   = (const float*)d_in[0];
  const int*   adj = (const int*)d_in[1];
  const float* E   = (const float*)d_in[2];
  const float* Wq  = (const float*)d_in[3];
  const float* Wk  = (const float*)d_in[4];
  const float* Wv  = (const float*)d_in[5];
  const float* We  = (const float*)d_in[6];
  const float* Wr  = (const float*)d_in[7];
  const float* Wo  = (const float*)d_in[8];
  float* out = (float*)d_out;

  float* Qs  = (float*)d_ws;                     // [2048][128]
  float* Ks  = Qs + (size_t)NN * DD;             // [2048][128]
  float* Vs  = Ks + (size_t)NN * DD;             // [2048][128]
  float* QWs = Vs + (size_t)NN * DD;             // [2048][64]

  hipLaunchKernelGGL(proj_kernel, dim3(NN / 8), dim3(384), 0, stream,
                     X, Wq, Wk, Wv, We, Wr, Qs, Ks, Vs, QWs);
  hipLaunchKernelGGL(attn_kernel, dim3(NN / 8), dim3(1024), 0, stream,
                     Qs, Ks, Vs, QWs, adj, E, Wo, out);
}

// Round 7
// 442.316 us; speedup vs baseline: 1.0215x; 1.0215x over previous
//
#include <hip/hip_runtime.h>
#include <math.h>

#define NN 2048
#define DD 128
#define HH 8
#define DHH 16
#define EDIM 8
#define EHID 32

// ---------------- Kernel 1: Q,K,V projections + folded edge projection QW ----
// 2 rows/block, grid 1024 x 384 threads -> 4 blocks/CU, 24 waves/CU.
__global__ __launch_bounds__(384) void proj_kernel(
    const float* __restrict__ X,
    const float* __restrict__ Wq, const float* __restrict__ Wk,
    const float* __restrict__ Wv, const float* __restrict__ We,
    const float* __restrict__ Wr,
    float* __restrict__ Qo, float* __restrict__ Ko,
    float* __restrict__ Vo, float* __restrict__ QWo) {
  __shared__ float x_lds[2][128];
  __shared__ float wer_lds[8][128];   // (We@Wr)[e][c]
  __shared__ float q_lds[2][128];
  const int t = threadIdx.x;
  const int i0 = blockIdx.x * 2;

  if (t < 256) x_lds[t >> 7][t & 127] = X[(size_t)i0 * 128 + t];

  if (t < 128) {
    float acc[EDIM];
#pragma unroll
    for (int e = 0; e < EDIM; ++e) acc[e] = 0.f;
    for (int k = 0; k < EHID; ++k) {
      const float wr = Wr[k * 128 + t];
#pragma unroll
      for (int e = 0; e < EDIM; ++e) acc[e] = fmaf(We[e * EHID + k], wr, acc[e]);
    }
#pragma unroll
    for (int e = 0; e < EDIM; ++e) wer_lds[e][t] = acc[e];
  }
  __syncthreads();

  const int mat = t >> 7;       // 0=Q 1=K 2=V
  const int c = t & 127;
  const float* __restrict__ W = (mat == 0) ? Wq : ((mat == 1) ? Wk : Wv);
  float a0 = 0.f, a1 = 0.f;
#pragma unroll 8
  for (int d = 0; d < 128; ++d) {
    const float w = W[d * 128 + c];
    a0 = fmaf(x_lds[0][d], w, a0);
    a1 = fmaf(x_lds[1][d], w, a1);
  }
  float* __restrict__ Out = (mat == 0) ? Qo : ((mat == 1) ? Ko : Vo);
  Out[(size_t)i0 * 128 + c] = a0;
  Out[(size_t)(i0 + 1) * 128 + c] = a1;
  if (mat == 0) { q_lds[0][c] = a0; q_lds[1][c] = a1; }
  __syncthreads();

  // QW[i][h*8+e] = sum_d Q[i][h*16+d] * Wer[e][h*16+d]
  if (t < 64) {
    const int h = t >> 3, e = t & 7;
#pragma unroll
    for (int r = 0; r < 2; ++r) {
      float s = 0.f;
#pragma unroll
      for (int d = 0; d < DHH; ++d)
        s = fmaf(q_lds[r][h * DHH + d], wer_lds[e][h * DHH + d], s);
      QWo[(size_t)(i0 + r) * 64 + h * 8 + e] = s;
    }
  }
}

// ---------------- Kernel 2: fused masked edge-biased attention + O@Wo -------
// grid 512 blocks (4 rows each), 512 threads.
// thread = (il 0..3, h 0..7, jo 0..15); each owns (i,h) over a 128-wide j slice.
// Software-pipelined: E/K loads for j-pair p+1 issued before computing pair p
// (ping-pong register sets A/B); V loads issued between the score chain and
// the PV update of the same pair (score chain covers their latency).
// Scores in log2 domain: leaky(raw/4)*log2e = 0.21640425*raw + 0.14426950*|raw|.
#define LOADEK(S, P) do {                                           \
    const int _j0 = (P) * 2;                                        \
    const float4* _e = ep + 2 * _j0;                                \
    e##S##0 = _e[0]; e##S##1 = _e[1]; e##S##2 = _e[2]; e##S##3 = _e[3]; \
    const float4* _k = kp + (size_t)_j0 * 32;                       \
    k##S##0 = _k[0];  k##S##1 = _k[1];  k##S##2 = _k[2];  k##S##3 = _k[3]; \
    k##S##4 = _k[32]; k##S##5 = _k[33]; k##S##6 = _k[34]; k##S##7 = _k[35]; \
  } while (0)

__global__ __launch_bounds__(512) void attn_kernel(
    const float* __restrict__ Qg, const float* __restrict__ Kg,
    const float* __restrict__ Vg, const float* __restrict__ QWg,
    const int* __restrict__ adj, const float* __restrict__ Eg,
    const float* __restrict__ Wo, float* __restrict__ out) {
  const int t = threadIdx.x;
  const int il = t & 3;
  const int h = (t >> 2) & 7;
  const int jo = t >> 5;              // 0..15
  const int i0 = blockIdx.x * 4;
  const int i = i0 + il;

  float4 q0, q1, q2, q3, qw0, qw1;
  {
    const float4* qp = (const float4*)(Qg + (size_t)i * 128 + h * 16);
    q0 = qp[0]; q1 = qp[1]; q2 = qp[2]; q3 = qp[3];
    const float4* wp = (const float4*)(QWg + (size_t)i * 64 + h * 8);
    qw0 = wp[0]; qw1 = wp[1];
  }

  float acc[16];
#pragma unroll
  for (int d = 0; d < 16; ++d) acc[d] = 0.f;
  float m = -INFINITY, mt = -INFINITY, l = 0.f;

  const int jbase = jo * 128;
  const int4* __restrict__ ap4 = (const int4*)(adj + (size_t)i * NN + jbase);
  const float4* __restrict__ ep = (const float4*)Eg + ((size_t)i * NN + jbase) * 2;
  const float4* __restrict__ kp = (const float4*)Kg + (size_t)jbase * 32 + h * 4;
  const float4* __restrict__ vp = (const float4*)Vg + (size_t)jbase * 32 + h * 4;

  // score for one j: QK dot + edge-bias dot, then leaky+mask+online softmax p
  auto score = [&](const float4 E0, const float4 E1,
                   const float4 K0, const float4 K1, const float4 K2, const float4 K3,
                   const int a) -> float {
    float s0 = q0.x * K0.x;    s0 = fmaf(q0.y, K0.y, s0);
    s0 = fmaf(q0.z, K0.z, s0); s0 = fmaf(q0.w, K0.w, s0);
    s0 = fmaf(q1.x, K1.x, s0); s0 = fmaf(q1.y, K1.y, s0);
    s0 = fmaf(q1.z, K1.z, s0); s0 = fmaf(q1.w, K1.w, s0);
    float s1 = q2.x * K2.x;    s1 = fmaf(q2.y, K2.y, s1);
    s1 = fmaf(q2.z, K2.z, s1); s1 = fmaf(q2.w, K2.w, s1);
    s1 = fmaf(q3.x, K3.x, s1); s1 = fmaf(q3.y, K3.y, s1);
    s1 = fmaf(q3.z, K3.z, s1); s1 = fmaf(q3.w, K3.w, s1);
    float b0 = qw0.x * E0.x;   b0 = fmaf(qw0.y, E0.y, b0);
    b0 = fmaf(qw0.z, E0.z, b0); b0 = fmaf(qw0.w, E0.w, b0);
    b0 = fmaf(qw1.x, E1.x, b0); b0 = fmaf(qw1.y, E1.y, b0);
    b0 = fmaf(qw1.z, E1.z, b0); b0 = fmaf(qw1.w, E1.w, b0);
    const float raw = (s0 + s1) + b0;
    float sc2 = fmaf(0.14426950f, fabsf(raw), 0.21640425f * raw);
    sc2 = (a > 0) ? sc2 : -1e9f;      // mask after leaky, like ref
    if (sc2 > mt) {                   // deferred-rescale online softmax (T13)
      const float r = exp2f(m - sc2);
      l *= r;
#pragma unroll
      for (int d = 0; d < 16; ++d) acc[d] *= r;
      m = sc2; mt = sc2 + 12.f;
    }
    const float p = exp2f(sc2 - m);
    l += p;
    return p;
  };
  auto pv = [&](const float p, const float4 V0, const float4 V1,
                const float4 V2, const float4 V3) {
    acc[0]  = fmaf(p, V0.x, acc[0]);  acc[1]  = fmaf(p, V0.y, acc[1]);
    acc[2]  = fmaf(p, V0.z, acc[2]);  acc[3]  = fmaf(p, V0.w, acc[3]);
    acc[4]  = fmaf(p, V1.x, acc[4]);  acc[5]  = fmaf(p, V1.y, acc[5]);
    acc[6]  = fmaf(p, V1.z, acc[6]);  acc[7]  = fmaf(p, V1.w, acc[7]);
    acc[8]  = fmaf(p, V2.x, acc[8]);  acc[9]  = fmaf(p, V2.y, acc[9]);
    acc[10] = fmaf(p, V2.z, acc[10]); acc[11] = fmaf(p, V2.w, acc[11]);
    acc[12] = fmaf(p, V3.x, acc[12]); acc[13] = fmaf(p, V3.y, acc[13]);
    acc[14] = fmaf(p, V3.z, acc[14]); acc[15] = fmaf(p, V3.w, acc[15]);
  };

  float4 eA0, eA1, eA2, eA3, kA0, kA1, kA2, kA3, kA4, kA5, kA6, kA7;
  float4 eB0, eB1, eB2, eB3, kB0, kB1, kB2, kB3, kB4, kB5, kB6, kB7;

  int4 a_cur = ap4[0];
  LOADEK(A, 0);
#pragma unroll 1
  for (int p2 = 0; p2 < 64; p2 += 2) {     // pair p covers j=2p, 2p+1
    const int g = p2 >> 1;
    const int4 a_nxt = ap4[g < 31 ? g + 1 : 31];
    LOADEK(B, p2 + 1);                     // prefetch E/K of pair p2+1
    {
      const float4* _v = vp + (size_t)(p2 * 2) * 32;  // V of pair p2 (j,j+1)
      const float4 v0 = _v[0],  v1 = _v[1],  v2 = _v[2],  v3 = _v[3];
      const float4 v4 = _v[32], v5 = _v[33], v6 = _v[34], v7 = _v[35];
      const float pa = score(eA0, eA1, kA0, kA1, kA2, kA3, a_cur.x);
      pv(pa, v0, v1, v2, v3);
      const float pb = score(eA2, eA3, kA4, kA5, kA6, kA7, a_cur.y);
      pv(pb, v4, v5, v6, v7);
    }
    LOADEK(A, p2 + 2 < 64 ? p2 + 2 : 63);  // prefetch E/K of pair p2+2
    {
      const float4* _v = vp + (size_t)(p2 * 2 + 2) * 32; // V of pair p2+1
      const float4 v0 = _v[0],  v1 = _v[1],  v2 = _v[2],  v3 = _v[3];
      const float4 v4 = _v[32], v5 = _v[33], v6 = _v[34], v7 = _v[35];
      const float pa = score(eB0, eB1, kB0, kB1, kB2, kB3, a_cur.z);
      pv(pa, v0, v1, v2, v3);
      const float pb = score(eB2, eB3, kB4, kB5, kB6, kB7, a_cur.w);
      pv(pb, v4, v5, v6, v7);
    }
    a_cur = a_nxt;
  }

  // ---- merge the 16 jo-partials per (il,h): LDS log-tree, 4 rounds ----
  // stride 18 floats between consecutive u -> 2-way bank alias only (free).
  __shared__ float mbuf[256 * 18];    // 18.4 KB
  __shared__ float o_lds[4][128];
  const int u = t & 31;               // (il,h) id
  for (int k = 8; k >= 1; k >>= 1) {
    if (jo >= k && jo < 2 * k) {
      float* b = mbuf + ((size_t)((jo - k) * 32 + u)) * 18;
      b[0] = m; b[1] = l;
#pragma unroll
      for (int d = 0; d < 16; ++d) b[2 + d] = acc[d];
    }
    __syncthreads();
    if (jo < k) {
      const float* b = mbuf + ((size_t)(jo * 32 + u)) * 18;
      const float m2 = b[0], l2 = b[1];
      const float M = fmaxf(m, m2);
      const float sa = exp2f(m - M);
      const float sb = exp2f(m2 - M);
      l = l * sa + l2 * sb;
#pragma unroll
      for (int d = 0; d < 16; ++d) acc[d] = acc[d] * sa + b[2 + d] * sb;
      m = M;
    }
    __syncthreads();
  }

  if (jo == 0) {
    const float inv = 1.f / l;
#pragma unroll
    for (int d = 0; d < 16; ++d) o_lds[il][h * 16 + d] = acc[d] * inv;
  }
  __syncthreads();

  // ---- epilogue: out = O @ Wo ----
  const int r = t >> 7;               // 0..3
  const int c = t & 127;
  float s = 0.f;
#pragma unroll 8
  for (int d = 0; d < 128; ++d)
    s = fmaf(o_lds[r][d], Wo[d * 128 + c], s);
  out[(size_t)(i0 + r) * 128 + c] = s;
}

extern "C" void kernel_launch(void* const* d_in, const int* in_sizes, int n_in,
                              void* d_out, int out_size, void* d_ws, size_t ws_size,
                              hipStream_t stream) {
  const float* X   = (const float*)d_in[0];
  const int*   adj = (const int*)d_in[1];
  const float* E   = (const float*)d_in[2];
  const float* Wq  = (const float*)d_in[3];
  const float* Wk  = (const float*)d_in[4];
  const float* Wv  = (const float*)d_in[5];
  const float* We  = (const float*)d_in[6];
  const float* Wr  = (const float*)d_in[7];
  const float* Wo  = (const float*)d_in[8];
  float* out = (float*)d_out;

  float* Qs  = (float*)d_ws;                     // [2048][128]
  float* Ks  = Qs + (size_t)NN * DD;             // [2048][128]
  float* Vs  = Ks + (size_t)NN * DD;             // [2048][128]
  float* QWs = Vs + (size_t)NN * DD;             // [2048][64]

  hipLaunchKernelGGL(proj_kernel, dim3(NN / 2), dim3(384), 0, stream,
                     X, Wq, Wk, Wv, We, Wr, Qs, Ks, Vs, QWs);
  hipLaunchKernelGGL(attn_kernel, dim3(NN / 4), dim3(512), 0, stream,
                     Qs, Ks, Vs, QWs, adj, E, Wo, out);
}

// Round 8
// 360.714 us; speedup vs baseline: 1.2526x; 1.2262x over previous
//
#include <hip/hip_runtime.h>
#include <math.h>

#define NN 2048
#define DD 128
#define HH 8
#define DHH 16
#define EDIM 8
#define EHID 32

typedef __attribute__((address_space(1))) const void GV;
typedef __attribute__((address_space(3))) void LV;

// ---------------- Kernel 1: Q,K,V projections + folded edge projection QW ----
__global__ __launch_bounds__(384) void proj_kernel(
    const float* __restrict__ X,
    const float* __restrict__ Wq, const float* __restrict__ Wk,
    const float* __restrict__ Wv, const float* __restrict__ We,
    const float* __restrict__ Wr,
    float* __restrict__ Qo, float* __restrict__ Ko,
    float* __restrict__ Vo, float* __restrict__ QWo) {
  __shared__ float x_lds[2][128];
  __shared__ float wer_lds[8][128];
  __shared__ float q_lds[2][128];
  const int t = threadIdx.x;
  const int i0 = blockIdx.x * 2;

  if (t < 256) x_lds[t >> 7][t & 127] = X[(size_t)i0 * 128 + t];

  if (t < 128) {
    float acc[EDIM];
#pragma unroll
    for (int e = 0; e < EDIM; ++e) acc[e] = 0.f;
    for (int k = 0; k < EHID; ++k) {
      const float wr = Wr[k * 128 + t];
#pragma unroll
      for (int e = 0; e < EDIM; ++e) acc[e] = fmaf(We[e * EHID + k], wr, acc[e]);
    }
#pragma unroll
    for (int e = 0; e < EDIM; ++e) wer_lds[e][t] = acc[e];
  }
  __syncthreads();

  const int mat = t >> 7;
  const int c = t & 127;
  const float* __restrict__ W = (mat == 0) ? Wq : ((mat == 1) ? Wk : Wv);
  float a0 = 0.f, a1 = 0.f;
#pragma unroll 8
  for (int d = 0; d < 128; ++d) {
    const float w = W[d * 128 + c];
    a0 = fmaf(x_lds[0][d], w, a0);
    a1 = fmaf(x_lds[1][d], w, a1);
  }
  float* __restrict__ Out = (mat == 0) ? Qo : ((mat == 1) ? Ko : Vo);
  Out[(size_t)i0 * 128 + c] = a0;
  Out[(size_t)(i0 + 1) * 128 + c] = a1;
  if (mat == 0) { q_lds[0][c] = a0; q_lds[1][c] = a1; }
  __syncthreads();

  if (t < 64) {
    const int h = t >> 3, e = t & 7;
#pragma unroll
    for (int r = 0; r < 2; ++r) {
      float s = 0.f;
#pragma unroll
      for (int d = 0; d < DHH; ++d)
        s = fmaf(q_lds[r][h * DHH + d], wer_lds[e][h * DHH + d], s);
      QWo[(size_t)(i0 + r) * 64 + h * 8 + e] = s;
    }
  }
}

// ---------------- Kernel 2: producer/consumer LDS-ring attention + O@Wo -----
// 320 threads: t<256 consumers (il 0..1, h 0..7, jo 0..15), wave 4 = producer.
// Producer DMA-stages K/V/E for step jj+3 each step (17 global_load_lds,
// counted vmcnt(34) -> 2 slots always in flight across raw barriers).
// LDS K/V slot layout: float4 chunk index = jo*32 + h + 8*qq (bank-quad = h).
// E slot: chunk = il*32 + jo*2 + half.
__global__ __launch_bounds__(320) void attn_kernel(
    const float* __restrict__ Qg, const float* __restrict__ Kg,
    const float* __restrict__ Vg, const float* __restrict__ QWg,
    const int* __restrict__ adj, const float* __restrict__ Eg,
    const float* __restrict__ Wo, float* __restrict__ out) {
  __shared__ float4 Ks_lds[4][512];   // 32 KB
  __shared__ float4 Vs_lds[4][512];   // 32 KB
  __shared__ float4 Es_lds[4][64];    // 4 KB
  __shared__ float mbuf[128 * 18];    // 9 KB
  __shared__ float o_lds[2][128];     // 1 KB

  const int t = threadIdx.x;
  const int i0 = blockIdx.x * 2;

  if (t >= 256) {
    // ================= producer wave =================
    const int lid = t - 256;
    const int hi = lid >> 5;          // 0/1: which jo-half per K/V inst
    const int r = lid & 31;
    const int h_p = r & 7, qq_p = r >> 3;
    const float* Kbase = Kg + (size_t)hi * 16384 + h_p * 16 + qq_p * 4;
    const float* Vbase = Vg + (size_t)hi * 16384 + h_p * 16 + qq_p * 4;
    const int il_e = lid >> 5;
    const int jo_e = (lid & 31) >> 1, half = lid & 1;
    const float* Ebase = Eg + ((size_t)(i0 + il_e) * 2048 + jo_e * 128) * 8 + half * 4;

    auto ISSUE = [&](int slot, int jj) {
      const float* kb = Kbase + (size_t)jj * 128;
      const float* vb = Vbase + (size_t)jj * 128;
      const float* eb = Ebase + (size_t)jj * 8;
#pragma unroll
      for (int j = 0; j < 8; ++j)
        __builtin_amdgcn_global_load_lds((GV*)(kb + j * 32768),
                                         (LV*)&Ks_lds[slot][j * 64], 16, 0, 0);
#pragma unroll
      for (int j = 0; j < 8; ++j)
        __builtin_amdgcn_global_load_lds((GV*)(vb + j * 32768),
                                         (LV*)&Vs_lds[slot][j * 64], 16, 0, 0);
      __builtin_amdgcn_global_load_lds((GV*)eb, (LV*)&Es_lds[slot][0], 16, 0, 0);
    };

    ISSUE(0, 0); ISSUE(1, 1); ISSUE(2, 2);
    asm volatile("s_waitcnt vmcnt(34)" ::: "memory");   // slot 0 ready
    __builtin_amdgcn_s_barrier();
    __builtin_amdgcn_sched_barrier(0);
    for (int jj = 0; jj < 128; ++jj) {
      if (jj < 125) {
        ISSUE((jj + 3) & 3, jj + 3);
        asm volatile("s_waitcnt vmcnt(34)" ::: "memory"); // slot jj+1 ready
      } else if (jj == 125) {
        asm volatile("s_waitcnt vmcnt(17)" ::: "memory");
      } else {
        asm volatile("s_waitcnt vmcnt(0)" ::: "memory");
      }
      __builtin_amdgcn_s_barrier();
      __builtin_amdgcn_sched_barrier(0);
    }
  } else {
    // ================= consumer waves =================
    const int il = t & 1;
    const int h = (t >> 1) & 7;
    const int jo = t >> 4;
    const int i = i0 + il;

    float4 q0, q1, q2, q3, qw0, qw1;
    {
      const float4* qp = (const float4*)(Qg + (size_t)i * 128 + h * 16);
      q0 = qp[0]; q1 = qp[1]; q2 = qp[2]; q3 = qp[3];
      const float4* wp = (const float4*)(QWg + (size_t)i * 64 + h * 8);
      qw0 = wp[0]; qw1 = wp[1];
    }

    float acc[16];
#pragma unroll
    for (int d = 0; d < 16; ++d) acc[d] = 0.f;
    float m = -INFINITY, mt = -INFINITY, l = 0.f;

    const int4* __restrict__ ap4 = (const int4*)(adj + (size_t)i * NN + jo * 128);

    auto score = [&](const float4 E0, const float4 E1,
                     const float4 K0, const float4 K1, const float4 K2,
                     const float4 K3, const int a) -> float {
      float s0 = q0.x * K0.x;    s0 = fmaf(q0.y, K0.y, s0);
      s0 = fmaf(q0.z, K0.z, s0); s0 = fmaf(q0.w, K0.w, s0);
      s0 = fmaf(q1.x, K1.x, s0); s0 = fmaf(q1.y, K1.y, s0);
      s0 = fmaf(q1.z, K1.z, s0); s0 = fmaf(q1.w, K1.w, s0);
      float s1 = q2.x * K2.x;    s1 = fmaf(q2.y, K2.y, s1);
      s1 = fmaf(q2.z, K2.z, s1); s1 = fmaf(q2.w, K2.w, s1);
      s1 = fmaf(q3.x, K3.x, s1); s1 = fmaf(q3.y, K3.y, s1);
      s1 = fmaf(q3.z, K3.z, s1); s1 = fmaf(q3.w, K3.w, s1);
      float b0 = qw0.x * E0.x;    b0 = fmaf(qw0.y, E0.y, b0);
      b0 = fmaf(qw0.z, E0.z, b0); b0 = fmaf(qw0.w, E0.w, b0);
      b0 = fmaf(qw1.x, E1.x, b0); b0 = fmaf(qw1.y, E1.y, b0);
      b0 = fmaf(qw1.z, E1.z, b0); b0 = fmaf(qw1.w, E1.w, b0);
      const float raw = (s0 + s1) + b0;
      float sc2 = fmaf(0.14426950f, fabsf(raw), 0.21640425f * raw);
      sc2 = (a > 0) ? sc2 : -1e9f;
      if (sc2 > mt) {
        const float rr = exp2f(m - sc2);
        l *= rr;
#pragma unroll
        for (int d = 0; d < 16; ++d) acc[d] *= rr;
        m = sc2; mt = sc2 + 12.f;
      }
      const float p = exp2f(sc2 - m);
      l += p;
      return p;
    };
    auto pv = [&](const float p, const float4 V0, const float4 V1,
                  const float4 V2, const float4 V3) {
      acc[0]  = fmaf(p, V0.x, acc[0]);  acc[1]  = fmaf(p, V0.y, acc[1]);
      acc[2]  = fmaf(p, V0.z, acc[2]);  acc[3]  = fmaf(p, V0.w, acc[3]);
      acc[4]  = fmaf(p, V1.x, acc[4]);  acc[5]  = fmaf(p, V1.y, acc[5]);
      acc[6]  = fmaf(p, V1.z, acc[6]);  acc[7]  = fmaf(p, V1.w, acc[7]);
      acc[8]  = fmaf(p, V2.x, acc[8]);  acc[9]  = fmaf(p, V2.y, acc[9]);
      acc[10] = fmaf(p, V2.z, acc[10]); acc[11] = fmaf(p, V2.w, acc[11]);
      acc[12] = fmaf(p, V3.x, acc[12]); acc[13] = fmaf(p, V3.y, acc[13]);
      acc[14] = fmaf(p, V3.z, acc[14]); acc[15] = fmaf(p, V3.w, acc[15]);
    };

    int4 a_cur = ap4[0];
    __builtin_amdgcn_s_barrier();          // matches producer prologue barrier
    __builtin_amdgcn_sched_barrier(0);

    for (int j4 = 0; j4 < 32; ++j4) {
      const int4 a_nxt = ap4[j4 < 31 ? j4 + 1 : 31];
#pragma unroll
      for (int u4 = 0; u4 < 4; ++u4) {
        const int jj = j4 * 4 + u4;
        const int slot = jj & 3;
        const int a = (u4 == 0) ? a_cur.x : (u4 == 1) ? a_cur.y
                    : (u4 == 2) ? a_cur.z : a_cur.w;
        const float4* kq = &Ks_lds[slot][jo * 32 + h];
        const float4 K0 = kq[0], K1 = kq[8], K2 = kq[16], K3 = kq[24];
        const float4* vq = &Vs_lds[slot][jo * 32 + h];
        const float4 V0 = vq[0], V1 = vq[8], V2 = vq[16], V3 = vq[24];
        const float4* eq = &Es_lds[slot][il * 32 + jo * 2];
        const float4 E0 = eq[0], E1 = eq[1];
        const float p = score(E0, E1, K0, K1, K2, K3, a);
        pv(p, V0, V1, V2, V3);
        __builtin_amdgcn_s_barrier();
        __builtin_amdgcn_sched_barrier(0);
      }
      a_cur = a_nxt;
    }

    // stash state for merge
    {
      const int u = t & 15;     // (il,h)
      // handled below in the shared merge section via registers m,l,acc
      (void)u;
    }
    // fallthrough to merge with live m, l, acc
    __syncthreads();
    const int u = t & 15;
    for (int k = 8; k >= 1; k >>= 1) {
      if (jo >= k && jo < 2 * k) {
        float* b = mbuf + ((size_t)((jo - k) * 16 + u)) * 18;
        b[0] = m; b[1] = l;
#pragma unroll
        for (int d = 0; d < 16; ++d) b[2 + d] = acc[d];
      }
      __syncthreads();
      if (jo < k) {
        const float* b = mbuf + ((size_t)(jo * 16 + u)) * 18;
        const float m2 = b[0], l2 = b[1];
        const float M = fmaxf(m, m2);
        const float sa = exp2f(m - M), sb = exp2f(m2 - M);
        l = l * sa + l2 * sb;
#pragma unroll
        for (int d = 0; d < 16; ++d) acc[d] = acc[d] * sa + b[2 + d] * sb;
        m = M;
      }
      __syncthreads();
    }
    if (jo == 0) {
      const float inv = 1.f / l;
#pragma unroll
      for (int d = 0; d < 16; ++d) o_lds[il][h * 16 + d] = acc[d] * inv;
    }
    __syncthreads();
    // epilogue: out = O @ Wo (256 threads cover 2 rows x 128 cols)
    const int r = t >> 7, c = t & 127;
    float s = 0.f;
#pragma unroll 8
    for (int d = 0; d < 128; ++d)
      s = fmaf(o_lds[r][d], Wo[d * 128 + c], s);
    out[(size_t)(i0 + r) * 128 + c] = s;
    return;
  }

  // producer joins the consumers' merge barriers
  __syncthreads();                           // matches consumers' first
  for (int k = 8; k >= 1; k >>= 1) { __syncthreads(); __syncthreads(); }
  __syncthreads();
}

extern "C" void kernel_launch(void* const* d_in, const int* in_sizes, int n_in,
                              void* d_out, int out_size, void* d_ws, size_t ws_size,
                              hipStream_t stream) {
  const float* X   = (const float*)d_in[0];
  const int*   adj = (const int*)d_in[1];
  const float* E   = (const float*)d_in[2];
  const float* Wq  = (const float*)d_in[3];
  const float* Wk  = (const float*)d_in[4];
  const float* Wv  = (const float*)d_in[5];
  const float* We  = (const float*)d_in[6];
  const float* Wr  = (const float*)d_in[7];
  const float* Wo  = (const float*)d_in[8];
  float* out = (float*)d_out;

  float* Qs  = (float*)d_ws;
  float* Ks  = Qs + (size_t)NN * DD;
  float* Vs  = Ks + (size_t)NN * DD;
  float* QWs = Vs + (size_t)NN * DD;

  hipLaunchKernelGGL(proj_kernel, dim3(NN / 2), dim3(384), 0, stream,
                     X, Wq, Wk, Wv, We, Wr, Qs, Ks, Vs, QWs);
  hipLaunchKernelGGL(attn_kernel, dim3(NN / 2), dim3(320), 0, stream,
                     Qs, Ks, Vs, QWs, adj, E, Wo, out);
}